// Round 12
// baseline (280.715 us; speedup 1.0000x reference)
//
#include <hip/hip_runtime.h>
#include <hip/hip_bf16.h>

#define N_NODES 50000
#define N_EDGES 400000
#define IN_CH 32
#define EPS 1e-5f
#define SCAN_NB ((N_NODES + 1023) / 1024)

#define HIST_B ((N_EDGES + 255) / 256)
#define WCT_TOT (3 * 320 * 64)
#define W2T_TOT (3 * 64 * 128)
#define RPK_B ((WCT_TOT + W2T_TOT + 255) / 256)
#define ENC_B ((N_NODES + 63) / 64)

typedef __attribute__((ext_vector_type(8))) short bh8;
typedef __attribute__((ext_vector_type(4))) float fx4;
typedef __attribute__((ext_vector_type(2))) float fx2;

static __device__ __forceinline__ unsigned int f2bf(float f) {
    __hip_bfloat16 h = __float2bfloat16(f);
    return (unsigned int)*(unsigned short*)&h;
}
static __device__ __forceinline__ unsigned short f2bfu(float f) {
    __hip_bfloat16 h = __float2bfloat16(f);
    return *(unsigned short*)&h;
}
static __device__ __forceinline__ float bflo(unsigned int u) { return __uint_as_float(u << 16); }

// ---------------- setup: hist | repack | MFMA encoder ----------------
__global__ __launch_bounds__(256) void setup_kernel(
    const int* __restrict__ ei, int* __restrict__ cnt,
    const float* __restrict__ W1, const float* __restrict__ Wr,
    const float* __restrict__ W2,
    unsigned short* __restrict__ WcT, unsigned short* __restrict__ W2T,
    const float* __restrict__ x, const float* __restrict__ encW,
    const float* __restrict__ encb, const float* __restrict__ encg,
    const float* __restrict__ encbeta, float* __restrict__ xout) {
    int b = blockIdx.x;
    if (b < HIST_B) {
        int e = b * 256 + threadIdx.x;
        if (e < N_EDGES) atomicAdd(&cnt[ei[N_EDGES + e]], 1);
        return;
    }
    b -= HIST_B;
    if (b < RPK_B) {
        int t = b * 256 + threadIdx.x;
        if (t < WCT_TOT) {
            int l = t / (320 * 64);
            int rem = t % (320 * 64);
            int j = rem / 64, c = rem % 64;
            float v;
            if (j < 128)      v = W1[(l * 128 + c) * 128 + j];
            else if (j < 256) v = W1[(l * 128 + 64 + c) * 128 + (j - 128)];
            else              v = Wr[(l * 64 + c) * 64 + (j - 256)];
            WcT[t] = f2bfu(v);
        } else if (t < WCT_TOT + W2T_TOT) {
            int t2 = t - WCT_TOT;
            int l = t2 / 8192, rem = t2 % 8192;
            int n = rem / 128, k = rem % 128;
            W2T[t2] = f2bfu(W2[l * 8192 + k * 64 + n]);
        }
        return;
    }
    b -= RPK_B;
    // ---- MFMA encoder: 64 nodes/block, 4 waves x 16-node tiles ----
    __shared__ unsigned short wT[64 * 32];  // encW^T bf16: [col][k]
    int tid = threadIdx.x;
    for (int t = tid; t < IN_CH * 64; t += 256) {
        int k = t >> 6, c = t & 63;
        wT[c * 32 + k] = f2bfu(encW[t]);
    }
    __syncthreads();
    int lane = tid & 63, wid = tid >> 6;
    int l15 = lane & 15, g4 = lane >> 4;
    int node0 = b * 64 + wid * 16;
    int arow = min(node0 + l15, N_NODES - 1);
    float4 xa = *(const float4*)(x + (size_t)arow * 32 + g4 * 8);
    float4 xb = *(const float4*)(x + (size_t)arow * 32 + g4 * 8 + 4);
    bh8 af;
    af[0] = (short)f2bfu(xa.x); af[1] = (short)f2bfu(xa.y);
    af[2] = (short)f2bfu(xa.z); af[3] = (short)f2bfu(xa.w);
    af[4] = (short)f2bfu(xb.x); af[5] = (short)f2bfu(xb.y);
    af[6] = (short)f2bfu(xb.z); af[7] = (short)f2bfu(xb.w);
    float cb[4], gvv[4], bvv[4];
    fx4 cf[4];
    #pragma unroll
    for (int nb = 0; nb < 4; ++nb) {
        int cc = nb * 16 + l15;
        cb[nb] = encb[cc]; gvv[nb] = encg[cc]; bvv[nb] = encbeta[cc];
        bh8 bf = *(const bh8*)&wT[(nb * 16 + l15) * 32 + g4 * 8];
        cf[nb] = __builtin_amdgcn_mfma_f32_16x16x32_bf16(
            af, bf, (fx4){0.f, 0.f, 0.f, 0.f}, 0, 0, 0);
    }
    float vals[4][4];
    #pragma unroll
    for (int nb = 0; nb < 4; ++nb)
        #pragma unroll
        for (int r = 0; r < 4; ++r) vals[nb][r] = cf[nb][r] + cb[nb];
    #pragma unroll
    for (int r = 0; r < 4; ++r) {
        float s = vals[0][r] + vals[1][r] + vals[2][r] + vals[3][r];
        s += __shfl_xor(s, 1, 16);
        s += __shfl_xor(s, 2, 16);
        s += __shfl_xor(s, 4, 16);
        s += __shfl_xor(s, 8, 16);
        float mu = s * (1.f / 64.f);
        float q = 0.f;
        #pragma unroll
        for (int nb = 0; nb < 4; ++nb) { float d = vals[nb][r] - mu; q += d * d; }
        q += __shfl_xor(q, 1, 16);
        q += __shfl_xor(q, 2, 16);
        q += __shfl_xor(q, 4, 16);
        q += __shfl_xor(q, 8, 16);
        float rs = rsqrtf(q * (1.f / 64.f) + EPS);
        int nd = node0 + g4 * 4 + r;
        if (nd < N_NODES) {
            #pragma unroll
            for (int nb = 0; nb < 4; ++nb)
                xout[(size_t)nd * 64 + nb * 16 + l15] =
                    (vals[nb][r] - mu) * rs * gvv[nb] + bvv[nb];
        }
    }
}

// ---------------- CSR scans ----------------
__global__ __launch_bounds__(1024) void scan1_kernel(const int* __restrict__ cnt,
                                                     int* __restrict__ exw,
                                                     int* __restrict__ bsum) {
    int b = blockIdx.x, t = threadIdx.x;
    int i = b * 1024 + t;
    int v = (i < N_NODES) ? cnt[i] : 0;
    int lane = t & 63, w = t >> 6;
    int s = v;
    #pragma unroll
    for (int off = 1; off < 64; off <<= 1) {
        int u = __shfl_up(s, off, 64);
        if (lane >= off) s += u;
    }
    __shared__ int ws[16];
    if (lane == 63) ws[w] = s;
    __syncthreads();
    if (t < 16) {
        int sv = ws[t];
        #pragma unroll
        for (int off = 1; off < 16; off <<= 1) {
            int u = __shfl_up(sv, off, 64);
            if (lane >= off) sv += u;
        }
        ws[t] = sv;
    }
    __syncthreads();
    int prefix = (w > 0) ? ws[w - 1] : 0;
    int incl = s + prefix;
    if (i < N_NODES) exw[i] = incl - v;
    if (t == 1023) bsum[b] = incl;
}

__global__ __launch_bounds__(1024) void scan3_kernel(const int* __restrict__ exw,
                                                     const int* __restrict__ bsum,
                                                     int* __restrict__ rp,
                                                     int* __restrict__ cnt) {
    __shared__ int pfx;
    __shared__ int total;
    int b = blockIdx.x, t = threadIdx.x;
    if (t < 64) {
        int v = (t < SCAN_NB) ? bsum[t] : 0;
        #pragma unroll
        for (int off = 1; off < 64; off <<= 1) {
            int u = __shfl_up(v, off, 64);
            if (t >= off) v += u;
        }
        if (b == 0 && t == 0) pfx = 0;
        if (b > 0 && t == b - 1) pfx = v;
        if (t == SCAN_NB - 1) total = v;
    }
    __syncthreads();
    int i = b * 1024 + t;
    if (i < N_NODES) {
        rp[i] = exw[i] + pfx;
        cnt[i] = 0;
    }
    if (b == 0 && t == 0) rp[N_NODES] = total;
}

__global__ void fill_kernel(const int* __restrict__ ei, const int* __restrict__ rp,
                            int* __restrict__ cur, int* __restrict__ el) {
    int e = blockIdx.x * 256 + threadIdx.x;
    if (e < N_EDGES) {
        int d = ei[N_EDGES + e];
        int p = atomicAdd(&cur[d], 1);
        el[rp[d] + p] = ei[e];
    }
}

// ---------------- fused9: barrier-free gather front-end (direct rp/el reads)
// 16-node tiles (N divisible by 16 -> no tail guards), 4 waves.
// mode 0: LN+GEMM only. mode 1: full. mode 2: gather+update only.
__global__ __launch_bounds__(256, 8) void fused9_kernel(
    float* __restrict__ x,
    const unsigned char* __restrict__ A8I, const unsigned char* __restrict__ B8I,
    const unsigned short* __restrict__ W2T, const float* __restrict__ b2,
    const int* __restrict__ rp, const int* __restrict__ el,
    const float* __restrict__ g, const float* __restrict__ bvec,
    const unsigned short* __restrict__ WcT, const float* __restrict__ b1,
    unsigned char* __restrict__ A8O, unsigned char* __restrict__ B8O,
    unsigned short* __restrict__ Rbf, int mode) {
    __shared__ float bufF[1088];          // xf rows stride 68 ; later h rows stride 33 (uints)
    __shared__ unsigned int slds[16][68]; // gathered S tile, bf16 pairs
    int tid = threadIdx.x;
    int lane = tid & 63, wid = tid >> 6;
    int l15 = lane & 15, g4 = lane >> 4;
    int base = blockIdx.x * 16;
    unsigned int* hU = (unsigned int*)bufF;
    int n = tid >> 4, sq = tid & 15;  // gather/LN mapping: 16 threads per row

    int col = wid * 16 + l15;         // epilogue column
    int nd_l = base + g4 * 4;         // epilogue row group

    if (mode != 0) {
        int nd_n = base + n;
        // direct CSR range (L1-broadcast lines, no staging barrier)
        int es = rp[nd_n], ee = rp[nd_n + 1];
        // own-node A row segment: 8 fp8 cols
        uint2 a0 = *(const uint2*)(A8I + (size_t)nd_n * 128 + sq * 8);
        // epilogue operand prefetch (independent; hidden under gather)
        float xpre[4], rpre[4];
        int rpv[5];
        #pragma unroll
        for (int r = 0; r < 4; ++r) {
            int nd = nd_l + r;
            xpre[r] = x[(size_t)nd * 64 + col];
            rpre[r] = bflo((unsigned int)Rbf[(size_t)nd * 64 + col]);
        }
        #pragma unroll
        for (int r = 0; r < 5; ++r) rpv[r] = rp[nd_l + r];

        float av[8], acc[8];
        {
            fx2 d0 = __builtin_amdgcn_cvt_pk_f32_fp8((int)a0.x, false);
            fx2 d1 = __builtin_amdgcn_cvt_pk_f32_fp8((int)a0.x, true);
            fx2 d2 = __builtin_amdgcn_cvt_pk_f32_fp8((int)a0.y, false);
            fx2 d3 = __builtin_amdgcn_cvt_pk_f32_fp8((int)a0.y, true);
            av[0] = d0.x; av[1] = d0.y; av[2] = d1.x; av[3] = d1.y;
            av[4] = d2.x; av[5] = d2.y; av[6] = d3.x; av[7] = d3.y;
        }
        #pragma unroll
        for (int i = 0; i < 8; ++i) acc[i] = 0.f;

        // ---- 8-deep batched gather, direct el reads ----
        int e2 = es;
        int cn = ee - e2; if (cn > 8) cn = 8;
        int srcs[8];
        uint2 bufv[8];
        #pragma unroll
        for (int j = 0; j < 8; ++j) if (j < cn) srcs[j] = el[e2 + j];
        #pragma unroll
        for (int j = 0; j < 8; ++j)
            if (j < cn) bufv[j] = *(const uint2*)(B8I + (size_t)srcs[j] * 128 + sq * 8);
        while (cn > 0) {
            #pragma unroll
            for (int j = 0; j < 8; ++j)
                if (j < cn) {
                    fx2 f0 = __builtin_amdgcn_cvt_pk_f32_fp8((int)bufv[j].x, false);
                    fx2 f1 = __builtin_amdgcn_cvt_pk_f32_fp8((int)bufv[j].x, true);
                    fx2 f2 = __builtin_amdgcn_cvt_pk_f32_fp8((int)bufv[j].y, false);
                    fx2 f3 = __builtin_amdgcn_cvt_pk_f32_fp8((int)bufv[j].y, true);
                    acc[0] += fmaxf(av[0] + f0.x, 0.f);
                    acc[1] += fmaxf(av[1] + f0.y, 0.f);
                    acc[2] += fmaxf(av[2] + f1.x, 0.f);
                    acc[3] += fmaxf(av[3] + f1.y, 0.f);
                    acc[4] += fmaxf(av[4] + f2.x, 0.f);
                    acc[5] += fmaxf(av[5] + f2.y, 0.f);
                    acc[6] += fmaxf(av[6] + f3.x, 0.f);
                    acc[7] += fmaxf(av[7] + f3.y, 0.f);
                }
            e2 += cn;
            cn = ee - e2; if (cn > 8) cn = 8;
            #pragma unroll
            for (int j = 0; j < 8; ++j) if (j < cn) srcs[j] = el[e2 + j];
            #pragma unroll
            for (int j = 0; j < 8; ++j)
                if (j < cn) bufv[j] = *(const uint2*)(B8I + (size_t)srcs[j] * 128 + sq * 8);
        }
        #pragma unroll
        for (int jj = 0; jj < 4; ++jj)
            slds[n][sq * 4 + jj] = f2bf(acc[2 * jj]) | (f2bf(acc[2 * jj + 1]) << 16);
        __syncthreads();

        // ---- S(16x128) @ W2T -> update x ; wave wid owns cols wid*16..+15 ----
        bh8 sa[4];
        #pragma unroll
        for (int ks = 0; ks < 4; ++ks)
            sa[ks] = *(const bh8*)&slds[l15][ks * 16 + g4 * 4];
        fx4 accm = (fx4){0.f, 0.f, 0.f, 0.f};
        #pragma unroll
        for (int ks = 0; ks < 4; ++ks) {
            bh8 bf = *(const bh8*)(W2T + ((size_t)(wid * 16 + l15) * 128 + ks * 32 + g4 * 8));
            accm = __builtin_amdgcn_mfma_f32_16x16x32_bf16(sa[ks], bf, accm, 0, 0, 0);
        }
        float b2c = b2[col];
        #pragma unroll
        for (int r = 0; r < 4; ++r) {
            int cv = rpv[r + 1] - rpv[r];
            float inv = cv > 0 ? 1.f / (float)cv : 0.f;
            float msk = cv > 0 ? 1.f : 0.f;
            int nd = nd_l + r;
            float xn = xpre[r] + accm[r] * inv + b2c * msk + rpre[r];
            x[(size_t)nd * 64 + col] = xn;
            if (mode == 1) bufF[(g4 * 4 + r) * 68 + col] = xn;
        }
        if (mode == 2) return;
        __syncthreads();
    }

    // ---- LN + ReLU: 16 threads per row, 4 cols each; write h bf16x2 stride 33 ----
    {
        float vv[4];
        if (mode == 0) {
            int nd = base + n;
            float4 v0 = ((const float4*)(x + (size_t)nd * 64))[sq];
            vv[0] = v0.x; vv[1] = v0.y; vv[2] = v0.z; vv[3] = v0.w;
        } else {
            #pragma unroll
            for (int i = 0; i < 4; ++i) vv[i] = bufF[n * 68 + sq * 4 + i];
        }
        float s = vv[0] + vv[1] + vv[2] + vv[3];
        s += __shfl_xor(s, 1, 16);
        s += __shfl_xor(s, 2, 16);
        s += __shfl_xor(s, 4, 16);
        s += __shfl_xor(s, 8, 16);
        float mu = s * (1.f / 64.f);
        float q = 0.f;
        #pragma unroll
        for (int i = 0; i < 4; ++i) { float d = vv[i] - mu; q += d * d; }
        q += __shfl_xor(q, 1, 16);
        q += __shfl_xor(q, 2, 16);
        q += __shfl_xor(q, 4, 16);
        q += __shfl_xor(q, 8, 16);
        float rs = rsqrtf(q * (1.f / 64.f) + EPS);
        float4 gg = *(const float4*)&g[sq * 4];
        float4 bb = *(const float4*)&bvec[sq * 4];
        float gv[4] = {gg.x, gg.y, gg.z, gg.w};
        float bv[4] = {bb.x, bb.y, bb.z, bb.w};
        __syncthreads();  // all bufF reads done before h overwrites
        #pragma unroll
        for (int jj = 0; jj < 2; ++jj) {
            float h0 = fmaxf((vv[2 * jj] - mu) * rs * gv[2 * jj] + bv[2 * jj], 0.f);
            float h1 = fmaxf((vv[2 * jj + 1] - mu) * rs * gv[2 * jj + 1] + bv[2 * jj + 1], 0.f);
            hU[n * 33 + sq * 2 + jj] = f2bf(h0) | (f2bf(h1) << 16);
        }
    }
    __syncthreads();

    // ---- GEMM2: h(16x64) @ Wc(64x320); wave does 5 of 20 col-blocks ----
    bh8 a2[2];
    #pragma unroll
    for (int ks = 0; ks < 2; ++ks)
        a2[ks] = *(const bh8*)&hU[l15 * 33 + ks * 16 + g4 * 4];
    int ndg = base + g4 * 4;
    #pragma unroll
    for (int nn = 0; nn < 5; ++nn) {
        int nb = wid * 5 + nn;
        fx4 c = (fx4){0.f, 0.f, 0.f, 0.f};
        #pragma unroll
        for (int ks = 0; ks < 2; ++ks) {
            bh8 bf = *(const bh8*)(WcT + ((size_t)(nb * 16 + l15) * 64 + ks * 32 + g4 * 8));
            c = __builtin_amdgcn_mfma_f32_16x16x32_bf16(a2[ks], bf, c, 0, 0, 0);
        }
        int colw = nb * 16 + l15;
        #pragma unroll
        for (int r = 0; r < 4; ++r) {
            int nd = ndg + r;
            float v = c[r];
            if (colw < 128) {
                unsigned int p = __builtin_amdgcn_cvt_pk_fp8_f32(v + b1[colw], 0.f, 0, false);
                A8O[(size_t)nd * 128 + colw] = (unsigned char)(p & 0xFF);
            } else if (colw < 256) {
                unsigned int p = __builtin_amdgcn_cvt_pk_fp8_f32(v, 0.f, 0, false);
                B8O[(size_t)nd * 128 + (colw - 128)] = (unsigned char)(p & 0xFF);
            } else {
                Rbf[(size_t)nd * 64 + (colw - 256)] = f2bfu(v);
            }
        }
    }
}

extern "C" void kernel_launch(void* const* d_in, const int* in_sizes, int n_in,
                              void* d_out, int out_size, void* d_ws, size_t ws_size,
                              hipStream_t stream) {
    const float* x       = (const float*)d_in[0];
    const int*   ei      = (const int*)d_in[1];
    const float* encW    = (const float*)d_in[2];
    const float* encb    = (const float*)d_in[3];
    const float* encg    = (const float*)d_in[4];
    const float* encbeta = (const float*)d_in[5];
    const float* lng     = (const float*)d_in[6];
    const float* lnb     = (const float*)d_in[7];
    const float* W1      = (const float*)d_in[8];
    const float* b1      = (const float*)d_in[9];
    const float* W2      = (const float*)d_in[10];
    const float* b2      = (const float*)d_in[11];
    const float* Wr      = (const float*)d_in[12];
    float* xout = (float*)d_out;

    char* ws = (char*)d_ws;
    size_t off = 0;
    auto alloc = [&](size_t bytes) -> void* {
        void* p = ws + off;
        off += (bytes + 255) & ~(size_t)255;
        return p;
    };
    unsigned short* WcT  = (unsigned short*)alloc(3 * 320 * 64 * sizeof(unsigned short));
    unsigned short* W2T  = (unsigned short*)alloc(3 * 64 * 128 * sizeof(unsigned short));
    unsigned char*  A80  = (unsigned char*)alloc((size_t)N_NODES * 128);
    unsigned char*  A81  = (unsigned char*)alloc((size_t)N_NODES * 128);
    unsigned char*  B80  = (unsigned char*)alloc((size_t)N_NODES * 128);
    unsigned char*  B81  = (unsigned char*)alloc((size_t)N_NODES * 128);
    unsigned short* Rbf  = (unsigned short*)alloc((size_t)N_NODES * 64 * sizeof(unsigned short));
    int*            cnt  = (int*)alloc(N_NODES * sizeof(int));
    int*            rp   = (int*)alloc((N_NODES + 1) * sizeof(int));
    int*            el   = (int*)alloc(N_EDGES * sizeof(int));
    int*            exw  = (int*)alloc(N_NODES * sizeof(int));
    int*            bsum = (int*)alloc(SCAN_NB * sizeof(int));

    hipMemsetAsync(cnt, 0, N_NODES * sizeof(int), stream);
    setup_kernel<<<HIST_B + RPK_B + ENC_B, 256, 0, stream>>>(
        ei, cnt, W1, Wr, W2, WcT, W2T, x, encW, encb, encg, encbeta, xout);
    scan1_kernel<<<SCAN_NB, 1024, 0, stream>>>(cnt, exw, bsum);
    scan3_kernel<<<SCAN_NB, 1024, 0, stream>>>(exw, bsum, rp, cnt);
    fill_kernel<<<(N_EDGES + 255) / 256, 256, 0, stream>>>(ei, rp, cnt, el);

    int gblocks = (N_NODES + 15) / 16;
    // layer 0: LN+GEMM only, writes pair0
    fused9_kernel<<<gblocks, 256, 0, stream>>>(
        xout, A80, B80, W2T, b2, rp, el, lng, lnb,
        WcT, b1, A80, B80, Rbf, 0);
    // layer 1: gather pair0 (layer0 W2), writes pair1
    fused9_kernel<<<gblocks, 256, 0, stream>>>(
        xout, A80, B80, W2T, b2, rp, el, lng + 64, lnb + 64,
        WcT + (size_t)1 * 320 * 64, b1 + 128, A81, B81, Rbf, 1);
    // layer 2: gather pair1 (layer1 W2), writes pair0
    fused9_kernel<<<gblocks, 256, 0, stream>>>(
        xout, A81, B81, W2T + (size_t)1 * 64 * 128, b2 + 64, rp, el, lng + 128, lnb + 128,
        WcT + (size_t)2 * 320 * 64, b1 + 256, A80, B80, Rbf, 1);
    // final: gather pair0 (layer2 W2), update only
    fused9_kernel<<<gblocks, 256, 0, stream>>>(
        xout, A80, B80, W2T + (size_t)2 * 64 * 128, b2 + 128, rp, el, lng, lnb,
        WcT, b1, A81, B81, Rbf, 2);
}

// Round 13
// 201.221 us; speedup vs baseline: 1.3951x; 1.3951x over previous
//
#include <hip/hip_runtime.h>
#include <hip/hip_bf16.h>

#define N_NODES 50000
#define N_EDGES 400000
#define IN_CH 32
#define EPS 1e-5f
#define SCAN_NB ((N_NODES + 1023) / 1024)
#define EL_CAP 384

#define HIST_B ((N_EDGES + 255) / 256)
#define WCT_TOT (3 * 320 * 64)
#define W2T_TOT (3 * 64 * 128)
#define RPK_B ((WCT_TOT + W2T_TOT + 255) / 256)
#define ENC_B ((N_NODES + 63) / 64)

typedef __attribute__((ext_vector_type(8))) short bh8;
typedef __attribute__((ext_vector_type(4))) float fx4;
typedef __attribute__((ext_vector_type(2))) float fx2;

static __device__ __forceinline__ unsigned int f2bf(float f) {
    __hip_bfloat16 h = __float2bfloat16(f);
    return (unsigned int)*(unsigned short*)&h;
}
static __device__ __forceinline__ unsigned short f2bfu(float f) {
    __hip_bfloat16 h = __float2bfloat16(f);
    return *(unsigned short*)&h;
}
static __device__ __forceinline__ float bflo(unsigned int u) { return __uint_as_float(u << 16); }

// ---------------- setup: hist | repack | MFMA encoder ----------------
__global__ __launch_bounds__(256) void setup_kernel(
    const int* __restrict__ ei, int* __restrict__ cnt,
    const float* __restrict__ W1, const float* __restrict__ Wr,
    const float* __restrict__ W2,
    unsigned short* __restrict__ WcT, unsigned short* __restrict__ W2T,
    const float* __restrict__ x, const float* __restrict__ encW,
    const float* __restrict__ encb, const float* __restrict__ encg,
    const float* __restrict__ encbeta, float* __restrict__ xout) {
    int b = blockIdx.x;
    if (b < HIST_B) {
        int e = b * 256 + threadIdx.x;
        if (e < N_EDGES) atomicAdd(&cnt[ei[N_EDGES + e]], 1);
        return;
    }
    b -= HIST_B;
    if (b < RPK_B) {
        int t = b * 256 + threadIdx.x;
        if (t < WCT_TOT) {
            int l = t / (320 * 64);
            int rem = t % (320 * 64);
            int j = rem / 64, c = rem % 64;
            float v;
            if (j < 128)      v = W1[(l * 128 + c) * 128 + j];
            else if (j < 256) v = W1[(l * 128 + 64 + c) * 128 + (j - 128)];
            else              v = Wr[(l * 64 + c) * 64 + (j - 256)];
            WcT[t] = f2bfu(v);
        } else if (t < WCT_TOT + W2T_TOT) {
            int t2 = t - WCT_TOT;
            int l = t2 / 8192, rem = t2 % 8192;
            int n = rem / 128, k = rem % 128;
            W2T[t2] = f2bfu(W2[l * 8192 + k * 64 + n]);
        }
        return;
    }
    b -= RPK_B;
    // ---- MFMA encoder: 64 nodes/block, 4 waves x 16-node tiles ----
    __shared__ unsigned short wT[64 * 32];  // encW^T bf16: [col][k]
    int tid = threadIdx.x;
    for (int t = tid; t < IN_CH * 64; t += 256) {
        int k = t >> 6, c = t & 63;
        wT[c * 32 + k] = f2bfu(encW[t]);
    }
    __syncthreads();
    int lane = tid & 63, wid = tid >> 6;
    int l15 = lane & 15, g4 = lane >> 4;
    int node0 = b * 64 + wid * 16;
    int arow = min(node0 + l15, N_NODES - 1);
    float4 xa = *(const float4*)(x + (size_t)arow * 32 + g4 * 8);
    float4 xb = *(const float4*)(x + (size_t)arow * 32 + g4 * 8 + 4);
    bh8 af;
    af[0] = (short)f2bfu(xa.x); af[1] = (short)f2bfu(xa.y);
    af[2] = (short)f2bfu(xa.z); af[3] = (short)f2bfu(xa.w);
    af[4] = (short)f2bfu(xb.x); af[5] = (short)f2bfu(xb.y);
    af[6] = (short)f2bfu(xb.z); af[7] = (short)f2bfu(xb.w);
    float cb[4], gvv[4], bvv[4];
    fx4 cf[4];
    #pragma unroll
    for (int nb = 0; nb < 4; ++nb) {
        int cc = nb * 16 + l15;
        cb[nb] = encb[cc]; gvv[nb] = encg[cc]; bvv[nb] = encbeta[cc];
        bh8 bf = *(const bh8*)&wT[(nb * 16 + l15) * 32 + g4 * 8];
        cf[nb] = __builtin_amdgcn_mfma_f32_16x16x32_bf16(
            af, bf, (fx4){0.f, 0.f, 0.f, 0.f}, 0, 0, 0);
    }
    float vals[4][4];
    #pragma unroll
    for (int nb = 0; nb < 4; ++nb)
        #pragma unroll
        for (int r = 0; r < 4; ++r) vals[nb][r] = cf[nb][r] + cb[nb];
    #pragma unroll
    for (int r = 0; r < 4; ++r) {
        float s = vals[0][r] + vals[1][r] + vals[2][r] + vals[3][r];
        s += __shfl_xor(s, 1, 16);
        s += __shfl_xor(s, 2, 16);
        s += __shfl_xor(s, 4, 16);
        s += __shfl_xor(s, 8, 16);
        float mu = s * (1.f / 64.f);
        float q = 0.f;
        #pragma unroll
        for (int nb = 0; nb < 4; ++nb) { float d = vals[nb][r] - mu; q += d * d; }
        q += __shfl_xor(q, 1, 16);
        q += __shfl_xor(q, 2, 16);
        q += __shfl_xor(q, 4, 16);
        q += __shfl_xor(q, 8, 16);
        float rs = rsqrtf(q * (1.f / 64.f) + EPS);
        int nd = node0 + g4 * 4 + r;
        if (nd < N_NODES) {
            #pragma unroll
            for (int nb = 0; nb < 4; ++nb)
                xout[(size_t)nd * 64 + nb * 16 + l15] =
                    (vals[nb][r] - mu) * rs * gvv[nb] + bvv[nb];
        }
    }
}

// ---------------- CSR scans ----------------
__global__ __launch_bounds__(1024) void scan1_kernel(const int* __restrict__ cnt,
                                                     int* __restrict__ exw,
                                                     int* __restrict__ bsum) {
    int b = blockIdx.x, t = threadIdx.x;
    int i = b * 1024 + t;
    int v = (i < N_NODES) ? cnt[i] : 0;
    int lane = t & 63, w = t >> 6;
    int s = v;
    #pragma unroll
    for (int off = 1; off < 64; off <<= 1) {
        int u = __shfl_up(s, off, 64);
        if (lane >= off) s += u;
    }
    __shared__ int ws[16];
    if (lane == 63) ws[w] = s;
    __syncthreads();
    if (t < 16) {
        int sv = ws[t];
        #pragma unroll
        for (int off = 1; off < 16; off <<= 1) {
            int u = __shfl_up(sv, off, 64);
            if (lane >= off) sv += u;
        }
        ws[t] = sv;
    }
    __syncthreads();
    int prefix = (w > 0) ? ws[w - 1] : 0;
    int incl = s + prefix;
    if (i < N_NODES) exw[i] = incl - v;
    if (t == 1023) bsum[b] = incl;
}

__global__ __launch_bounds__(1024) void scan3_kernel(const int* __restrict__ exw,
                                                     const int* __restrict__ bsum,
                                                     int* __restrict__ rp,
                                                     int* __restrict__ cnt) {
    __shared__ int pfx;
    __shared__ int total;
    int b = blockIdx.x, t = threadIdx.x;
    if (t < 64) {
        int v = (t < SCAN_NB) ? bsum[t] : 0;
        #pragma unroll
        for (int off = 1; off < 64; off <<= 1) {
            int u = __shfl_up(v, off, 64);
            if (t >= off) v += u;
        }
        if (b == 0 && t == 0) pfx = 0;
        if (b > 0 && t == b - 1) pfx = v;
        if (t == SCAN_NB - 1) total = v;
    }
    __syncthreads();
    int i = b * 1024 + t;
    if (i < N_NODES) {
        rp[i] = exw[i] + pfx;
        cnt[i] = 0;
    }
    if (b == 0 && t == 0) rp[N_NODES] = total;
}

__global__ void fill_kernel(const int* __restrict__ ei, const int* __restrict__ rp,
                            int* __restrict__ cur, int* __restrict__ el) {
    int e = blockIdx.x * 256 + threadIdx.x;
    if (e < N_EDGES) {
        int d = ei[N_EDGES + e];
        int p = atomicAdd(&cur[d], 1);
        el[rp[d] + p] = ei[e];
    }
}

// ---------------- fused8 (proven round-11 structure): 16-node tiles, 4 waves
// mode 0: LN+GEMM only. mode 1: full. mode 2: gather+update only.
__global__ __launch_bounds__(256, 8) void fused8_kernel(
    float* __restrict__ x,
    const unsigned char* __restrict__ A8I, const unsigned char* __restrict__ B8I,
    const unsigned short* __restrict__ W2T, const float* __restrict__ b2,
    const int* __restrict__ rp, const int* __restrict__ el,
    const float* __restrict__ g, const float* __restrict__ bvec,
    const unsigned short* __restrict__ WcT, const float* __restrict__ b1,
    unsigned char* __restrict__ A8O, unsigned char* __restrict__ B8O,
    unsigned short* __restrict__ Rbf, int mode) {
    __shared__ float bufF[1088];          // xf rows stride 68 ; later h rows stride 33 (uints)
    __shared__ unsigned int slds[16][68]; // gathered S tile, bf16 pairs
    __shared__ int el_lds[EL_CAP];
    __shared__ int rp_lds[17];
    int tid = threadIdx.x;
    int lane = tid & 63, wid = tid >> 6;
    int l15 = lane & 15, g4 = lane >> 4;
    int base = blockIdx.x * 16;
    unsigned int* hU = (unsigned int*)bufF;
    int n = tid >> 4, sq = tid & 15;  // gather/LN mapping: 16 threads per row

    int col = wid * 16 + l15;         // epilogue column
    int nd_l = base + g4 * 4;         // epilogue row group

    if (mode != 0) {
        if (tid < 17) rp_lds[tid] = rp[min(base + tid, N_NODES)];
        __syncthreads();
        int e0 = rp_lds[0];
        int nE = rp_lds[16] - e0;
        bool inl = (nE <= EL_CAP);
        if (inl) for (int t = tid; t < nE; t += 256) el_lds[t] = el[e0 + t];

        // own-node A row segment: 8 fp8 cols per thread
        int nd_g = base + n;
        float av[8], acc[8];
        {
            uint2 a0 = *(const uint2*)(A8I + (size_t)min(nd_g, N_NODES - 1) * 128 + sq * 8);
            fx2 d0 = __builtin_amdgcn_cvt_pk_f32_fp8((int)a0.x, false);
            fx2 d1 = __builtin_amdgcn_cvt_pk_f32_fp8((int)a0.x, true);
            fx2 d2 = __builtin_amdgcn_cvt_pk_f32_fp8((int)a0.y, false);
            fx2 d3 = __builtin_amdgcn_cvt_pk_f32_fp8((int)a0.y, true);
            av[0] = d0.x; av[1] = d0.y; av[2] = d1.x; av[3] = d1.y;
            av[4] = d2.x; av[5] = d2.y; av[6] = d3.x; av[7] = d3.y;
        }
        #pragma unroll
        for (int i = 0; i < 8; ++i) acc[i] = 0.f;

        // early epilogue operand prefetch (latency hidden under gather)
        float xpre[4], rpre[4];
        #pragma unroll
        for (int r = 0; r < 4; ++r) {
            int nd = min(nd_l + r, N_NODES - 1);
            xpre[r] = x[(size_t)nd * 64 + col];
            rpre[r] = bflo((unsigned int)Rbf[(size_t)nd * 64 + col]);
        }
        __syncthreads();  // el_lds ready

        // ---- 8-deep batched gather: 8 B per thread per edge ----
        int es = rp_lds[n] - e0, ee = rp_lds[n + 1] - e0;
        int e2 = es;
        int cn = ee - e2; if (cn > 8) cn = 8;
        uint2 bufv[8];
        #pragma unroll
        for (int j = 0; j < 8; ++j)
            if (j < cn) {
                int src = inl ? el_lds[e2 + j] : el[e0 + e2 + j];
                bufv[j] = *(const uint2*)(B8I + (size_t)src * 128 + sq * 8);
            }
        while (cn > 0) {
            #pragma unroll
            for (int j = 0; j < 8; ++j)
                if (j < cn) {
                    fx2 f0 = __builtin_amdgcn_cvt_pk_f32_fp8((int)bufv[j].x, false);
                    fx2 f1 = __builtin_amdgcn_cvt_pk_f32_fp8((int)bufv[j].x, true);
                    fx2 f2 = __builtin_amdgcn_cvt_pk_f32_fp8((int)bufv[j].y, false);
                    fx2 f3 = __builtin_amdgcn_cvt_pk_f32_fp8((int)bufv[j].y, true);
                    acc[0] += fmaxf(av[0] + f0.x, 0.f);
                    acc[1] += fmaxf(av[1] + f0.y, 0.f);
                    acc[2] += fmaxf(av[2] + f1.x, 0.f);
                    acc[3] += fmaxf(av[3] + f1.y, 0.f);
                    acc[4] += fmaxf(av[4] + f2.x, 0.f);
                    acc[5] += fmaxf(av[5] + f2.y, 0.f);
                    acc[6] += fmaxf(av[6] + f3.x, 0.f);
                    acc[7] += fmaxf(av[7] + f3.y, 0.f);
                }
            e2 += cn;
            cn = ee - e2; if (cn > 8) cn = 8;
            #pragma unroll
            for (int j = 0; j < 8; ++j)
                if (j < cn) {
                    int src = inl ? el_lds[e2 + j] : el[e0 + e2 + j];
                    bufv[j] = *(const uint2*)(B8I + (size_t)src * 128 + sq * 8);
                }
        }
        #pragma unroll
        for (int jj = 0; jj < 4; ++jj)
            slds[n][sq * 4 + jj] = f2bf(acc[2 * jj]) | (f2bf(acc[2 * jj + 1]) << 16);
        __syncthreads();

        // ---- S(16x128) @ W2T -> update x ; wave wid owns cols wid*16..+15 ----
        bh8 sa[4];
        #pragma unroll
        for (int ks = 0; ks < 4; ++ks)
            sa[ks] = *(const bh8*)&slds[l15][ks * 16 + g4 * 4];
        fx4 accm = (fx4){0.f, 0.f, 0.f, 0.f};
        #pragma unroll
        for (int ks = 0; ks < 4; ++ks) {
            bh8 bf = *(const bh8*)(W2T + ((size_t)(wid * 16 + l15) * 128 + ks * 32 + g4 * 8));
            accm = __builtin_amdgcn_mfma_f32_16x16x32_bf16(sa[ks], bf, accm, 0, 0, 0);
        }
        float b2c = b2[col];
        #pragma unroll
        for (int r = 0; r < 4; ++r) {
            int lcl = g4 * 4 + r;
            int cv = rp_lds[lcl + 1] - rp_lds[lcl];
            float inv = cv > 0 ? 1.f / (float)cv : 0.f;
            float msk = cv > 0 ? 1.f : 0.f;
            int nd = nd_l + r;
            float xn = xpre[r] + accm[r] * inv + b2c * msk + rpre[r];
            if (nd < N_NODES) x[(size_t)nd * 64 + col] = xn;
            if (mode == 1) bufF[lcl * 68 + col] = xn;
        }
        if (mode == 2) return;
        __syncthreads();
    }

    // ---- LN + ReLU: 16 threads per row, 4 cols each; write h bf16x2 stride 33 ----
    {
        float vv[4];
        if (mode == 0) {
            int nd = base + n;
            float4 v0 = make_float4(0.f, 0.f, 0.f, 0.f);
            if (nd < N_NODES) v0 = ((const float4*)(x + (size_t)nd * 64))[sq];
            vv[0] = v0.x; vv[1] = v0.y; vv[2] = v0.z; vv[3] = v0.w;
        } else {
            #pragma unroll
            for (int i = 0; i < 4; ++i) vv[i] = bufF[n * 68 + sq * 4 + i];
        }
        float s = vv[0] + vv[1] + vv[2] + vv[3];
        s += __shfl_xor(s, 1, 16);
        s += __shfl_xor(s, 2, 16);
        s += __shfl_xor(s, 4, 16);
        s += __shfl_xor(s, 8, 16);
        float mu = s * (1.f / 64.f);
        float q = 0.f;
        #pragma unroll
        for (int i = 0; i < 4; ++i) { float d = vv[i] - mu; q += d * d; }
        q += __shfl_xor(q, 1, 16);
        q += __shfl_xor(q, 2, 16);
        q += __shfl_xor(q, 4, 16);
        q += __shfl_xor(q, 8, 16);
        float rs = rsqrtf(q * (1.f / 64.f) + EPS);
        float4 gg = *(const float4*)&g[sq * 4];
        float4 bb = *(const float4*)&bvec[sq * 4];
        float gv[4] = {gg.x, gg.y, gg.z, gg.w};
        float bv[4] = {bb.x, bb.y, bb.z, bb.w};
        __syncthreads();  // all bufF reads done before h overwrites
        #pragma unroll
        for (int jj = 0; jj < 2; ++jj) {
            float h0 = fmaxf((vv[2 * jj] - mu) * rs * gv[2 * jj] + bv[2 * jj], 0.f);
            float h1 = fmaxf((vv[2 * jj + 1] - mu) * rs * gv[2 * jj + 1] + bv[2 * jj + 1], 0.f);
            hU[n * 33 + sq * 2 + jj] = f2bf(h0) | (f2bf(h1) << 16);
        }
    }
    __syncthreads();

    // ---- GEMM2: h(16x64) @ Wc(64x320); wave does 5 of 20 col-blocks ----
    bh8 a2[2];
    #pragma unroll
    for (int ks = 0; ks < 2; ++ks)
        a2[ks] = *(const bh8*)&hU[l15 * 33 + ks * 16 + g4 * 4];
    int ndg = base + g4 * 4;
    #pragma unroll
    for (int nn = 0; nn < 5; ++nn) {
        int nb = wid * 5 + nn;
        fx4 c = (fx4){0.f, 0.f, 0.f, 0.f};
        #pragma unroll
        for (int ks = 0; ks < 2; ++ks) {
            bh8 bf = *(const bh8*)(WcT + ((size_t)(nb * 16 + l15) * 64 + ks * 32 + g4 * 8));
            c = __builtin_amdgcn_mfma_f32_16x16x32_bf16(a2[ks], bf, c, 0, 0, 0);
        }
        int colw = nb * 16 + l15;
        #pragma unroll
        for (int r = 0; r < 4; ++r) {
            int nd = ndg + r;
            if (nd >= N_NODES) continue;
            float v = c[r];
            if (colw < 128) {
                unsigned int p = __builtin_amdgcn_cvt_pk_fp8_f32(v + b1[colw], 0.f, 0, false);
                A8O[(size_t)nd * 128 + colw] = (unsigned char)(p & 0xFF);
            } else if (colw < 256) {
                unsigned int p = __builtin_amdgcn_cvt_pk_fp8_f32(v, 0.f, 0, false);
                B8O[(size_t)nd * 128 + (colw - 128)] = (unsigned char)(p & 0xFF);
            } else {
                Rbf[(size_t)nd * 64 + (colw - 256)] = f2bfu(v);
            }
        }
    }
}

extern "C" void kernel_launch(void* const* d_in, const int* in_sizes, int n_in,
                              void* d_out, int out_size, void* d_ws, size_t ws_size,
                              hipStream_t stream) {
    const float* x       = (const float*)d_in[0];
    const int*   ei      = (const int*)d_in[1];
    const float* encW    = (const float*)d_in[2];
    const float* encb    = (const float*)d_in[3];
    const float* encg    = (const float*)d_in[4];
    const float* encbeta = (const float*)d_in[5];
    const float* lng     = (const float*)d_in[6];
    const float* lnb     = (const float*)d_in[7];
    const float* W1      = (const float*)d_in[8];
    const float* b1      = (const float*)d_in[9];
    const float* W2      = (const float*)d_in[10];
    const float* b2      = (const float*)d_in[11];
    const float* Wr      = (const float*)d_in[12];
    float* xout = (float*)d_out;

    char* ws = (char*)d_ws;
    size_t off = 0;
    auto alloc = [&](size_t bytes) -> void* {
        void* p = ws + off;
        off += (bytes + 255) & ~(size_t)255;
        return p;
    };
    unsigned short* WcT  = (unsigned short*)alloc(3 * 320 * 64 * sizeof(unsigned short));
    unsigned short* W2T  = (unsigned short*)alloc(3 * 64 * 128 * sizeof(unsigned short));
    unsigned char*  A80  = (unsigned char*)alloc((size_t)N_NODES * 128);
    unsigned char*  A81  = (unsigned char*)alloc((size_t)N_NODES * 128);
    unsigned char*  B80  = (unsigned char*)alloc((size_t)N_NODES * 128);
    unsigned char*  B81  = (unsigned char*)alloc((size_t)N_NODES * 128);
    unsigned short* Rbf  = (unsigned short*)alloc((size_t)N_NODES * 64 * sizeof(unsigned short));
    int*            cnt  = (int*)alloc(N_NODES * sizeof(int));
    int*            rp   = (int*)alloc((N_NODES + 1) * sizeof(int));
    int*            el   = (int*)alloc(N_EDGES * sizeof(int));
    int*            exw  = (int*)alloc(N_NODES * sizeof(int));
    int*            bsum = (int*)alloc(SCAN_NB * sizeof(int));

    hipMemsetAsync(cnt, 0, N_NODES * sizeof(int), stream);
    setup_kernel<<<HIST_B + RPK_B + ENC_B, 256, 0, stream>>>(
        ei, cnt, W1, Wr, W2, WcT, W2T, x, encW, encb, encg, encbeta, xout);
    scan1_kernel<<<SCAN_NB, 1024, 0, stream>>>(cnt, exw, bsum);
    scan3_kernel<<<SCAN_NB, 1024, 0, stream>>>(exw, bsum, rp, cnt);
    fill_kernel<<<(N_EDGES + 255) / 256, 256, 0, stream>>>(ei, rp, cnt, el);

    int gblocks = (N_NODES + 15) / 16;
    // layer 0: LN+GEMM only, writes pair0
    fused8_kernel<<<gblocks, 256, 0, stream>>>(
        xout, A80, B80, W2T, b2, rp, el, lng, lnb,
        WcT, b1, A80, B80, Rbf, 0);
    // layer 1: gather pair0 (layer0 W2), writes pair1
    fused8_kernel<<<gblocks, 256, 0, stream>>>(
        xout, A80, B80, W2T, b2, rp, el, lng + 64, lnb + 64,
        WcT + (size_t)1 * 320 * 64, b1 + 128, A81, B81, Rbf, 1);
    // layer 2: gather pair1 (layer1 W2), writes pair0
    fused8_kernel<<<gblocks, 256, 0, stream>>>(
        xout, A81, B81, W2T + (size_t)1 * 64 * 128, b2 + 64, rp, el, lng + 128, lnb + 128,
        WcT + (size_t)2 * 320 * 64, b1 + 256, A80, B80, Rbf, 1);
    // final: gather pair0 (layer2 W2), update only
    fused8_kernel<<<gblocks, 256, 0, stream>>>(
        xout, A80, B80, W2T + (size_t)2 * 64 * 128, b2 + 128, rp, el, lng, lnb,
        WcT, b1, A81, B81, Rbf, 2);
}

// Round 14
// 194.719 us; speedup vs baseline: 1.4416x; 1.0334x over previous
//
#include <hip/hip_runtime.h>
#include <hip/hip_bf16.h>

#define N_NODES 50000
#define N_EDGES 400000
#define IN_CH 32
#define EPS 1e-5f
#define SCAN_NB ((N_NODES + 1023) / 1024)
#define EL_CAP 384

#define HIST_B ((N_EDGES + 255) / 256)
#define WCT_TOT (3 * 320 * 64)
#define W2T_TOT (3 * 64 * 128)
#define RPK_B ((WCT_TOT + W2T_TOT + 255) / 256)
#define ENC_B ((N_NODES + 63) / 64)

typedef __attribute__((ext_vector_type(8))) short bh8;
typedef __attribute__((ext_vector_type(4))) float fx4;
typedef __attribute__((ext_vector_type(2))) float fx2;

static __device__ __forceinline__ unsigned int f2bf(float f) {
    __hip_bfloat16 h = __float2bfloat16(f);
    return (unsigned int)*(unsigned short*)&h;
}
static __device__ __forceinline__ unsigned short f2bfu(float f) {
    __hip_bfloat16 h = __float2bfloat16(f);
    return *(unsigned short*)&h;
}
static __device__ __forceinline__ float bflo(unsigned int u) { return __uint_as_float(u << 16); }

// ---------------- setup: hist | repack | MFMA encoder ----------------
__global__ __launch_bounds__(256) void setup_kernel(
    const int* __restrict__ ei, int* __restrict__ cnt,
    const float* __restrict__ W1, const float* __restrict__ Wr,
    const float* __restrict__ W2,
    unsigned short* __restrict__ WcT, unsigned short* __restrict__ W2T,
    const float* __restrict__ x, const float* __restrict__ encW,
    const float* __restrict__ encb, const float* __restrict__ encg,
    const float* __restrict__ encbeta, float* __restrict__ xout) {
    int b = blockIdx.x;
    if (b < HIST_B) {
        int e = b * 256 + threadIdx.x;
        if (e < N_EDGES) atomicAdd(&cnt[ei[N_EDGES + e]], 1);
        return;
    }
    b -= HIST_B;
    if (b < RPK_B) {
        int t = b * 256 + threadIdx.x;
        if (t < WCT_TOT) {
            int l = t / (320 * 64);
            int rem = t % (320 * 64);
            int j = rem / 64, c = rem % 64;
            float v;
            if (j < 128)      v = W1[(l * 128 + c) * 128 + j];
            else if (j < 256) v = W1[(l * 128 + 64 + c) * 128 + (j - 128)];
            else              v = Wr[(l * 64 + c) * 64 + (j - 256)];
            WcT[t] = f2bfu(v);
        } else if (t < WCT_TOT + W2T_TOT) {
            int t2 = t - WCT_TOT;
            int l = t2 / 8192, rem = t2 % 8192;
            int n = rem / 128, k = rem % 128;
            W2T[t2] = f2bfu(W2[l * 8192 + k * 64 + n]);
        }
        return;
    }
    b -= RPK_B;
    // ---- MFMA encoder: 64 nodes/block, 4 waves x 16-node tiles ----
    __shared__ unsigned short wT[64 * 32];  // encW^T bf16: [col][k]
    int tid = threadIdx.x;
    for (int t = tid; t < IN_CH * 64; t += 256) {
        int k = t >> 6, c = t & 63;
        wT[c * 32 + k] = f2bfu(encW[t]);
    }
    __syncthreads();
    int lane = tid & 63, wid = tid >> 6;
    int l15 = lane & 15, g4 = lane >> 4;
    int node0 = b * 64 + wid * 16;
    int arow = min(node0 + l15, N_NODES - 1);
    float4 xa = *(const float4*)(x + (size_t)arow * 32 + g4 * 8);
    float4 xb = *(const float4*)(x + (size_t)arow * 32 + g4 * 8 + 4);
    bh8 af;
    af[0] = (short)f2bfu(xa.x); af[1] = (short)f2bfu(xa.y);
    af[2] = (short)f2bfu(xa.z); af[3] = (short)f2bfu(xa.w);
    af[4] = (short)f2bfu(xb.x); af[5] = (short)f2bfu(xb.y);
    af[6] = (short)f2bfu(xb.z); af[7] = (short)f2bfu(xb.w);
    float cb[4], gvv[4], bvv[4];
    fx4 cf[4];
    #pragma unroll
    for (int nb = 0; nb < 4; ++nb) {
        int cc = nb * 16 + l15;
        cb[nb] = encb[cc]; gvv[nb] = encg[cc]; bvv[nb] = encbeta[cc];
        bh8 bf = *(const bh8*)&wT[(nb * 16 + l15) * 32 + g4 * 8];
        cf[nb] = __builtin_amdgcn_mfma_f32_16x16x32_bf16(
            af, bf, (fx4){0.f, 0.f, 0.f, 0.f}, 0, 0, 0);
    }
    float vals[4][4];
    #pragma unroll
    for (int nb = 0; nb < 4; ++nb)
        #pragma unroll
        for (int r = 0; r < 4; ++r) vals[nb][r] = cf[nb][r] + cb[nb];
    #pragma unroll
    for (int r = 0; r < 4; ++r) {
        float s = vals[0][r] + vals[1][r] + vals[2][r] + vals[3][r];
        s += __shfl_xor(s, 1, 16);
        s += __shfl_xor(s, 2, 16);
        s += __shfl_xor(s, 4, 16);
        s += __shfl_xor(s, 8, 16);
        float mu = s * (1.f / 64.f);
        float q = 0.f;
        #pragma unroll
        for (int nb = 0; nb < 4; ++nb) { float d = vals[nb][r] - mu; q += d * d; }
        q += __shfl_xor(q, 1, 16);
        q += __shfl_xor(q, 2, 16);
        q += __shfl_xor(q, 4, 16);
        q += __shfl_xor(q, 8, 16);
        float rs = rsqrtf(q * (1.f / 64.f) + EPS);
        int nd = node0 + g4 * 4 + r;
        if (nd < N_NODES) {
            #pragma unroll
            for (int nb = 0; nb < 4; ++nb)
                xout[(size_t)nd * 64 + nb * 16 + l15] =
                    (vals[nb][r] - mu) * rs * gvv[nb] + bvv[nb];
        }
    }
}

// ---------------- CSR scans ----------------
__global__ __launch_bounds__(1024) void scan1_kernel(const int* __restrict__ cnt,
                                                     int* __restrict__ exw,
                                                     int* __restrict__ bsum) {
    int b = blockIdx.x, t = threadIdx.x;
    int i = b * 1024 + t;
    int v = (i < N_NODES) ? cnt[i] : 0;
    int lane = t & 63, w = t >> 6;
    int s = v;
    #pragma unroll
    for (int off = 1; off < 64; off <<= 1) {
        int u = __shfl_up(s, off, 64);
        if (lane >= off) s += u;
    }
    __shared__ int ws[16];
    if (lane == 63) ws[w] = s;
    __syncthreads();
    if (t < 16) {
        int sv = ws[t];
        #pragma unroll
        for (int off = 1; off < 16; off <<= 1) {
            int u = __shfl_up(sv, off, 64);
            if (lane >= off) sv += u;
        }
        ws[t] = sv;
    }
    __syncthreads();
    int prefix = (w > 0) ? ws[w - 1] : 0;
    int incl = s + prefix;
    if (i < N_NODES) exw[i] = incl - v;
    if (t == 1023) bsum[b] = incl;
}

__global__ __launch_bounds__(1024) void scan3_kernel(const int* __restrict__ exw,
                                                     const int* __restrict__ bsum,
                                                     int* __restrict__ rp,
                                                     int* __restrict__ cnt) {
    __shared__ int pfx;
    __shared__ int total;
    int b = blockIdx.x, t = threadIdx.x;
    if (t < 64) {
        int v = (t < SCAN_NB) ? bsum[t] : 0;
        #pragma unroll
        for (int off = 1; off < 64; off <<= 1) {
            int u = __shfl_up(v, off, 64);
            if (t >= off) v += u;
        }
        if (b == 0 && t == 0) pfx = 0;
        if (b > 0 && t == b - 1) pfx = v;
        if (t == SCAN_NB - 1) total = v;
    }
    __syncthreads();
    int i = b * 1024 + t;
    if (i < N_NODES) {
        rp[i] = exw[i] + pfx;
        cnt[i] = 0;
    }
    if (b == 0 && t == 0) rp[N_NODES] = total;
}

__global__ void fill_kernel(const int* __restrict__ ei, const int* __restrict__ rp,
                            int* __restrict__ cur, int* __restrict__ el) {
    int e = blockIdx.x * 256 + threadIdx.x;
    if (e < N_EDGES) {
        int d = ei[N_EDGES + e];
        int p = atomicAdd(&cur[d], 1);
        el[rp[d] + p] = ei[e];
    }
}

// ---------------- fused10: xR residual-carrier scheme
// xR = x_new + R (fp32), written once per layer by GEMM2; replaces x-write + Rbf.
// mode 0: LN+GEMM (x from global; xR0 = x0 + R0). mode 1: update(from xR)+LN+GEMM.
// mode 2: update only -> write final x to d_out.
__global__ __launch_bounds__(256, 8) void fused10_kernel(
    float* __restrict__ x, float* __restrict__ xR,
    const unsigned char* __restrict__ A8I, const unsigned char* __restrict__ B8I,
    const unsigned short* __restrict__ W2T, const float* __restrict__ b2,
    const int* __restrict__ rp, const int* __restrict__ el,
    const float* __restrict__ g, const float* __restrict__ bvec,
    const unsigned short* __restrict__ WcT, const float* __restrict__ b1,
    unsigned char* __restrict__ A8O, unsigned char* __restrict__ B8O, int mode) {
    __shared__ float bufF[1088];          // xf rows stride 68 ; later h rows stride 33 (uints)
    __shared__ unsigned int slds[16][68]; // gathered S tile (bf16 pairs); later xn fp32 copy
    __shared__ int el_lds[EL_CAP];
    __shared__ int rp_lds[17];
    float* slds_f = (float*)slds;
    int tid = threadIdx.x;
    int lane = tid & 63, wid = tid >> 6;
    int l15 = lane & 15, g4 = lane >> 4;
    int base = blockIdx.x * 16;
    unsigned int* hU = (unsigned int*)bufF;
    int n = tid >> 4, sq = tid & 15;  // gather/LN mapping: 16 threads per row

    int col = wid * 16 + l15;         // epilogue column
    int nd_l = base + g4 * 4;         // epilogue row group

    if (mode != 0) {
        if (tid < 17) rp_lds[tid] = rp[min(base + tid, N_NODES)];
        __syncthreads();
        int e0 = rp_lds[0];
        int nE = rp_lds[16] - e0;
        bool inl = (nE <= EL_CAP);
        if (inl) for (int t = tid; t < nE; t += 256) el_lds[t] = el[e0 + t];

        // own-node A row segment: 8 fp8 cols per thread
        int nd_g = base + n;
        float av[8], acc[8];
        {
            uint2 a0 = *(const uint2*)(A8I + (size_t)min(nd_g, N_NODES - 1) * 128 + sq * 8);
            fx2 d0 = __builtin_amdgcn_cvt_pk_f32_fp8((int)a0.x, false);
            fx2 d1 = __builtin_amdgcn_cvt_pk_f32_fp8((int)a0.x, true);
            fx2 d2 = __builtin_amdgcn_cvt_pk_f32_fp8((int)a0.y, false);
            fx2 d3 = __builtin_amdgcn_cvt_pk_f32_fp8((int)a0.y, true);
            av[0] = d0.x; av[1] = d0.y; av[2] = d1.x; av[3] = d1.y;
            av[4] = d2.x; av[5] = d2.y; av[6] = d3.x; av[7] = d3.y;
        }
        #pragma unroll
        for (int i = 0; i < 8; ++i) acc[i] = 0.f;

        // early epilogue operand prefetch (latency hidden under gather)
        float xpre[4];
        #pragma unroll
        for (int r = 0; r < 4; ++r) {
            int nd = min(nd_l + r, N_NODES - 1);
            xpre[r] = xR[(size_t)nd * 64 + col];
        }
        __syncthreads();  // el_lds ready

        // ---- 8-deep batched gather: 8 B per thread per edge ----
        int es = rp_lds[n] - e0, ee = rp_lds[n + 1] - e0;
        int e2 = es;
        int cn = ee - e2; if (cn > 8) cn = 8;
        uint2 bufv[8];
        #pragma unroll
        for (int j = 0; j < 8; ++j)
            if (j < cn) {
                int src = inl ? el_lds[e2 + j] : el[e0 + e2 + j];
                bufv[j] = *(const uint2*)(B8I + (size_t)src * 128 + sq * 8);
            }
        while (cn > 0) {
            #pragma unroll
            for (int j = 0; j < 8; ++j)
                if (j < cn) {
                    fx2 f0 = __builtin_amdgcn_cvt_pk_f32_fp8((int)bufv[j].x, false);
                    fx2 f1 = __builtin_amdgcn_cvt_pk_f32_fp8((int)bufv[j].x, true);
                    fx2 f2 = __builtin_amdgcn_cvt_pk_f32_fp8((int)bufv[j].y, false);
                    fx2 f3 = __builtin_amdgcn_cvt_pk_f32_fp8((int)bufv[j].y, true);
                    acc[0] += fmaxf(av[0] + f0.x, 0.f);
                    acc[1] += fmaxf(av[1] + f0.y, 0.f);
                    acc[2] += fmaxf(av[2] + f1.x, 0.f);
                    acc[3] += fmaxf(av[3] + f1.y, 0.f);
                    acc[4] += fmaxf(av[4] + f2.x, 0.f);
                    acc[5] += fmaxf(av[5] + f2.y, 0.f);
                    acc[6] += fmaxf(av[6] + f3.x, 0.f);
                    acc[7] += fmaxf(av[7] + f3.y, 0.f);
                }
            e2 += cn;
            cn = ee - e2; if (cn > 8) cn = 8;
            #pragma unroll
            for (int j = 0; j < 8; ++j)
                if (j < cn) {
                    int src = inl ? el_lds[e2 + j] : el[e0 + e2 + j];
                    bufv[j] = *(const uint2*)(B8I + (size_t)src * 128 + sq * 8);
                }
        }
        #pragma unroll
        for (int jj = 0; jj < 4; ++jj)
            slds[n][sq * 4 + jj] = f2bf(acc[2 * jj]) | (f2bf(acc[2 * jj + 1]) << 16);
        __syncthreads();

        // ---- S(16x128) @ W2T -> x_new ; wave wid owns cols wid*16..+15 ----
        bh8 sa[4];
        #pragma unroll
        for (int ks = 0; ks < 4; ++ks)
            sa[ks] = *(const bh8*)&slds[l15][ks * 16 + g4 * 4];
        fx4 accm = (fx4){0.f, 0.f, 0.f, 0.f};
        #pragma unroll
        for (int ks = 0; ks < 4; ++ks) {
            bh8 bf = *(const bh8*)(W2T + ((size_t)(wid * 16 + l15) * 128 + ks * 32 + g4 * 8));
            accm = __builtin_amdgcn_mfma_f32_16x16x32_bf16(sa[ks], bf, accm, 0, 0, 0);
        }
        float b2c = b2[col];
        #pragma unroll
        for (int r = 0; r < 4; ++r) {
            int lcl = g4 * 4 + r;
            int cv = rp_lds[lcl + 1] - rp_lds[lcl];
            float inv = cv > 0 ? 1.f / (float)cv : 0.f;
            float msk = cv > 0 ? 1.f : 0.f;
            float xn = xpre[r] + accm[r] * inv + b2c * msk;
            if (mode == 2) x[(size_t)(nd_l + r) * 64 + col] = xn;  // final output
            else           bufF[lcl * 68 + col] = xn;
        }
        if (mode == 2) return;
        __syncthreads();
    }

    // ---- LN + ReLU: 16 threads per row, 4 cols each ----
    {
        float vv[4];
        if (mode == 0) {
            int nd = base + n;
            float4 v0 = ((const float4*)(x + (size_t)nd * 64))[sq];
            vv[0] = v0.x; vv[1] = v0.y; vv[2] = v0.z; vv[3] = v0.w;
        } else {
            #pragma unroll
            for (int i = 0; i < 4; ++i) vv[i] = bufF[n * 68 + sq * 4 + i];
        }
        float s = vv[0] + vv[1] + vv[2] + vv[3];
        s += __shfl_xor(s, 1, 16);
        s += __shfl_xor(s, 2, 16);
        s += __shfl_xor(s, 4, 16);
        s += __shfl_xor(s, 8, 16);
        float mu = s * (1.f / 64.f);
        float q = 0.f;
        #pragma unroll
        for (int i = 0; i < 4; ++i) { float d = vv[i] - mu; q += d * d; }
        q += __shfl_xor(q, 1, 16);
        q += __shfl_xor(q, 2, 16);
        q += __shfl_xor(q, 4, 16);
        q += __shfl_xor(q, 8, 16);
        float rs = rsqrtf(q * (1.f / 64.f) + EPS);
        float4 gg = *(const float4*)&g[sq * 4];
        float4 bb = *(const float4*)&bvec[sq * 4];
        float gv[4] = {gg.x, gg.y, gg.z, gg.w};
        float bv[4] = {bb.x, bb.y, bb.z, bb.w};
        __syncthreads();  // all bufF/slds reads done before overwrites
        // stash xn (or x0 for mode 0) for the xR write in GEMM2
        #pragma unroll
        for (int i = 0; i < 4; ++i) slds_f[n * 68 + sq * 4 + i] = vv[i];
        #pragma unroll
        for (int jj = 0; jj < 2; ++jj) {
            float h0 = fmaxf((vv[2 * jj] - mu) * rs * gv[2 * jj] + bv[2 * jj], 0.f);
            float h1 = fmaxf((vv[2 * jj + 1] - mu) * rs * gv[2 * jj + 1] + bv[2 * jj + 1], 0.f);
            hU[n * 33 + sq * 2 + jj] = f2bf(h0) | (f2bf(h1) << 16);
        }
    }
    __syncthreads();

    // ---- GEMM2: h(16x64) @ Wc(64x320); wave does 5 of 20 col-blocks ----
    bh8 a2[2];
    #pragma unroll
    for (int ks = 0; ks < 2; ++ks)
        a2[ks] = *(const bh8*)&hU[l15 * 33 + ks * 16 + g4 * 4];
    int ndg = base + g4 * 4;
    #pragma unroll
    for (int nn = 0; nn < 5; ++nn) {
        int nb = wid * 5 + nn;
        fx4 c = (fx4){0.f, 0.f, 0.f, 0.f};
        #pragma unroll
        for (int ks = 0; ks < 2; ++ks) {
            bh8 bf = *(const bh8*)(WcT + ((size_t)(nb * 16 + l15) * 64 + ks * 32 + g4 * 8));
            c = __builtin_amdgcn_mfma_f32_16x16x32_bf16(a2[ks], bf, c, 0, 0, 0);
        }
        int colw = nb * 16 + l15;
        #pragma unroll
        for (int r = 0; r < 4; ++r) {
            int nd = ndg + r;
            float v = c[r];
            if (colw < 128) {
                unsigned int p = __builtin_amdgcn_cvt_pk_fp8_f32(v + b1[colw], 0.f, 0, false);
                A8O[(size_t)nd * 128 + colw] = (unsigned char)(p & 0xFF);
            } else if (colw < 256) {
                unsigned int p = __builtin_amdgcn_cvt_pk_fp8_f32(v, 0.f, 0, false);
                B8O[(size_t)nd * 128 + (colw - 128)] = (unsigned char)(p & 0xFF);
            } else {
                int c2 = colw - 256;
                xR[(size_t)nd * 64 + c2] = slds_f[(g4 * 4 + r) * 68 + c2] + v;
            }
        }
    }
}

extern "C" void kernel_launch(void* const* d_in, const int* in_sizes, int n_in,
                              void* d_out, int out_size, void* d_ws, size_t ws_size,
                              hipStream_t stream) {
    const float* x       = (const float*)d_in[0];
    const int*   ei      = (const int*)d_in[1];
    const float* encW    = (const float*)d_in[2];
    const float* encb    = (const float*)d_in[3];
    const float* encg    = (const float*)d_in[4];
    const float* encbeta = (const float*)d_in[5];
    const float* lng     = (const float*)d_in[6];
    const float* lnb     = (const float*)d_in[7];
    const float* W1      = (const float*)d_in[8];
    const float* b1      = (const float*)d_in[9];
    const float* W2      = (const float*)d_in[10];
    const float* b2      = (const float*)d_in[11];
    const float* Wr      = (const float*)d_in[12];
    float* xout = (float*)d_out;

    char* ws = (char*)d_ws;
    size_t off = 0;
    auto alloc = [&](size_t bytes) -> void* {
        void* p = ws + off;
        off += (bytes + 255) & ~(size_t)255;
        return p;
    };
    unsigned short* WcT  = (unsigned short*)alloc(3 * 320 * 64 * sizeof(unsigned short));
    unsigned short* W2T  = (unsigned short*)alloc(3 * 64 * 128 * sizeof(unsigned short));
    unsigned char*  A80  = (unsigned char*)alloc((size_t)N_NODES * 128);
    unsigned char*  A81  = (unsigned char*)alloc((size_t)N_NODES * 128);
    unsigned char*  B80  = (unsigned char*)alloc((size_t)N_NODES * 128);
    unsigned char*  B81  = (unsigned char*)alloc((size_t)N_NODES * 128);
    float*          xR   = (float*)alloc((size_t)N_NODES * 64 * sizeof(float));
    int*            cnt  = (int*)alloc(N_NODES * sizeof(int));
    int*            rp   = (int*)alloc((N_NODES + 1) * sizeof(int));
    int*            el   = (int*)alloc(N_EDGES * sizeof(int));
    int*            exw  = (int*)alloc(N_NODES * sizeof(int));
    int*            bsum = (int*)alloc(SCAN_NB * sizeof(int));

    hipMemsetAsync(cnt, 0, N_NODES * sizeof(int), stream);
    setup_kernel<<<HIST_B + RPK_B + ENC_B, 256, 0, stream>>>(
        ei, cnt, W1, Wr, W2, WcT, W2T, x, encW, encb, encg, encbeta, xout);
    scan1_kernel<<<SCAN_NB, 1024, 0, stream>>>(cnt, exw, bsum);
    scan3_kernel<<<SCAN_NB, 1024, 0, stream>>>(exw, bsum, rp, cnt);
    fill_kernel<<<(N_EDGES + 255) / 256, 256, 0, stream>>>(ei, rp, cnt, el);

    int gblocks = (N_NODES + 15) / 16;
    // layer 0: LN+GEMM only (x0 from d_out); writes A0/B0 + xR0 = x0 + R0
    fused10_kernel<<<gblocks, 256, 0, stream>>>(
        xout, xR, A80, B80, W2T, b2, rp, el, lng, lnb,
        WcT, b1, A80, B80, 0);
    // layer 1: gather pair0 (layer0 W2); writes A1/B1 + xR1
    fused10_kernel<<<gblocks, 256, 0, stream>>>(
        xout, xR, A80, B80, W2T, b2, rp, el, lng + 64, lnb + 64,
        WcT + (size_t)1 * 320 * 64, b1 + 128, A81, B81, 1);
    // layer 2: gather pair1 (layer1 W2); writes A0/B0 + xR2
    fused10_kernel<<<gblocks, 256, 0, stream>>>(
        xout, xR, A81, B81, W2T + (size_t)1 * 64 * 128, b2 + 64, rp, el, lng + 128, lnb + 128,
        WcT + (size_t)2 * 320 * 64, b1 + 256, A80, B80, 1);
    // final: gather pair0 (layer2 W2), update only -> d_out
    fused10_kernel<<<gblocks, 256, 0, stream>>>(
        xout, xR, A80, B80, W2T + (size_t)2 * 64 * 128, b2 + 128, rp, el, lng, lnb,
        WcT, b1, A81, B81, 2);
}